// Round 1
// baseline (13.687 us; speedup 1.0000x reference)
//
#include <hip/hip_runtime.h>

// Problem constants (B=1024, I=128, H=512, O=16)
#define B_DIM 1024
#define I_DIM 128
#define H_DIM 512
#define O_CNT 16

// Full 64-lane butterfly reduction (wave = 64 on CDNA4, not 32).
__device__ __forceinline__ float wave_reduce_sum(float v) {
#pragma unroll
    for (int off = 32; off > 0; off >>= 1)
        v += __shfl_xor(v, off, 64);
    return v;
}

// Kernel A: u[o*H + h] = sum_k W2[o, h, k] * W3[o, k]
// One wave per (o, h) row: 512 floats = 128 float4; lane reads f4[lane], f4[lane+64].
__global__ __launch_bounds__(256) void k_w2w3(const float* __restrict__ W2,
                                              const float* __restrict__ W3,
                                              float* __restrict__ u) {
    const int wid  = (blockIdx.x * 256 + threadIdx.x) >> 6;  // global wave id [0, 8192)
    const int lane = threadIdx.x & 63;
    const int o = wid >> 9;      // / 512
    const int h = wid & 511;
    const float4* row = (const float4*)(W2 + ((size_t)o * H_DIM + h) * H_DIM);
    const float4* w3  = (const float4*)(W3 + (size_t)o * H_DIM);
    float4 a0 = row[lane];
    float4 a1 = row[lane + 64];
    float4 b0 = w3[lane];
    float4 b1 = w3[lane + 64];
    float acc = a0.x * b0.x + a0.y * b0.y + a0.z * b0.z + a0.w * b0.w
              + a1.x * b1.x + a1.y * b1.y + a1.z * b1.z + a1.w * b1.w;
    acc = wave_reduce_sum(acc);
    if (lane == 0) u[wid] = acc;
}

// Kernel B: v[o*I + i] = sum_h W1[o, i, h] * u[o*H + h]
// One wave per (o, i) row: identical 512-float dot pattern.
__global__ __launch_bounds__(256) void k_w1u(const float* __restrict__ W1,
                                             const float* __restrict__ u,
                                             float* __restrict__ v) {
    const int wid  = (blockIdx.x * 256 + threadIdx.x) >> 6;  // [0, 2048)
    const int lane = threadIdx.x & 63;
    const int o = wid >> 7;      // / 128
    const int i = wid & 127;
    const float4* row = (const float4*)(W1 + ((size_t)o * I_DIM + i) * H_DIM);
    const float4* uo  = (const float4*)(u + (size_t)o * H_DIM);
    float4 a0 = row[lane];
    float4 a1 = row[lane + 64];
    float4 b0 = uo[lane];
    float4 b1 = uo[lane + 64];
    float acc = a0.x * b0.x + a0.y * b0.y + a0.z * b0.z + a0.w * b0.w
              + a1.x * b1.x + a1.y * b1.y + a1.z * b1.z + a1.w * b1.w;
    acc = wave_reduce_sum(acc);
    if (lane == 0) v[wid] = acc;
}

// Kernel C: out[b] = sum_i state[b, i] * v[opt[b]*I + i]
// One wave per sample: 128 floats = 64 float2; lane reads f2[lane].
__global__ __launch_bounds__(256) void k_out(const float* __restrict__ state,
                                             const int* __restrict__ option,
                                             const float* __restrict__ v,
                                             float* __restrict__ out) {
    const int b    = (blockIdx.x * 256 + threadIdx.x) >> 6;  // [0, 1024)
    const int lane = threadIdx.x & 63;
    const int o = option[b];     // 0..15
    const float2* srow = (const float2*)(state + (size_t)b * I_DIM);
    const float2* vrow = (const float2*)(v + (size_t)o * I_DIM);
    float2 s = srow[lane];
    float2 w = vrow[lane];
    float acc = s.x * w.x + s.y * w.y;
    acc = wave_reduce_sum(acc);
    if (lane == 0) out[b] = acc;
}

extern "C" void kernel_launch(void* const* d_in, const int* in_sizes, int n_in,
                              void* d_out, int out_size, void* d_ws, size_t ws_size,
                              hipStream_t stream) {
    const float* state  = (const float*)d_in[0];
    // d_in[1] = action, unused by the reference forward.
    const float* W1     = (const float*)d_in[2];
    const float* W2     = (const float*)d_in[3];
    const float* W3     = (const float*)d_in[4];
    const int*   option = (const int*)d_in[5];
    float* out = (float*)d_out;

    float* u = (float*)d_ws;                       // 16*512 floats = 32 KiB
    float* v = u + O_CNT * H_DIM;                  // 16*128 floats =  8 KiB

    // A: 16*512 = 8192 waves -> 2048 blocks of 256 threads
    k_w2w3<<<2048, 256, 0, stream>>>(W2, W3, u);
    // B: 16*128 = 2048 waves -> 512 blocks
    k_w1u<<<512, 256, 0, stream>>>(W1, u, v);
    // C: 1024 waves -> 256 blocks
    k_out<<<256, 256, 0, stream>>>(state, option, v, out);
}